// Round 4
// baseline (253.104 us; speedup 1.0000x reference)
//
#include <hip/hip_runtime.h>

// SSIM (win=7, valid) fused single-pass kernel for (32,3,512,512) fp32 inputs.
// 96 images of 512x512 -> mean over 96x506x506 S map.
//
// R4: amortized cross-lane exchange. One wave per block; each lane owns 8
// output cols (64x8=512, full row). Vertical 7-row running sums V[5][8] in
// regs; horizontal 7-col window slides serially in regs (2 adds/quantity/px);
// only 6 halo V values per quantity come from lane+1 via __shfl_down, once
// per row (30 shuffles per 8 px vs 20 per 2 px in R3). No LDS, no barriers
// in the loop. Loads: 2x dwordx4 per array per row, dense across the wave.

namespace {
constexpr int W      = 512;
constexpr int HH     = 512;
constexpr int NIMG   = 96;
constexpr int OW     = 506;
constexpr int RSTRIP = 23;   // 22 * 23 = 506 output rows exactly
constexpr int NSTRIP = 22;
// S = (2 ux uy + C1)(2 vxy + C2) / ((ux^2+uy^2+C1)(vx+vy+C2)); with U = 49*u
// window sums, every term carries 1/2401 which cancels in the ratio:
constexpr float D1      = 0.2401f;                  // C1 * 49^2
constexpr float D2      = 2.1609f;                  // C2 * 49^2
constexpr float COVN    = 49.0f / 48.0f;            // NP/(NP-1)
constexpr float COV2    = 2.0f * COVN;
constexpr float K49COV  = 49.0f * COVN;
constexpr float K49COV2 = 2.0f * 49.0f * COVN;
constexpr double NPIX   = 96.0 * 506.0 * 506.0;     // 24,579,456
}

__global__ __launch_bounds__(64, 3) void ssim_main(const float* __restrict__ X,
                                                   const float* __restrict__ Y,
                                                   double* __restrict__ acc)
{
    const int lane = threadIdx.x;              // 0..63 (one wave per block)
    const int img  = blockIdx.y;
    const int r0   = blockIdx.x * RSTRIP;      // first output row of strip
    const int c0   = lane * 8;                 // this lane's first column

    const float* xb = X + (size_t)img * (W * HH) + c0;
    const float* yb = Y + (size_t)img * (W * HH) + c0;

    // vertical running sums over the 7-row window, per own column 0..7:
    // V[0]=sum x, V[1]=sum y, V[2]=sum x^2, V[3]=sum y^2, V[4]=sum x*y
    float V[5][8];
#pragma unroll
    for (int q = 0; q < 5; q++)
#pragma unroll
        for (int i = 0; i < 8; i++) V[q][i] = 0.0f;

    float xr[8], yr[8], xo[8], yo[8];

    auto load_row = [&](int r, float (&dx)[8], float (&dy)[8]) {
        const float* px = xb + (size_t)r * W;
        const float* py = yb + (size_t)r * W;
        float4 a = *(const float4*)px;
        float4 b = *(const float4*)(px + 4);
        dx[0] = a.x; dx[1] = a.y; dx[2] = a.z; dx[3] = a.w;
        dx[4] = b.x; dx[5] = b.y; dx[6] = b.z; dx[7] = b.w;
        float4 e = *(const float4*)py;
        float4 f = *(const float4*)(py + 4);
        dy[0] = e.x; dy[1] = e.y; dy[2] = e.z; dy[3] = e.w;
        dy[4] = f.x; dy[5] = f.y; dy[6] = f.z; dy[7] = f.w;
    };

    // warm-up: rows r0 .. r0+5
#pragma unroll
    for (int k = 0; k < 6; k++) {
        load_row(r0 + k, xr, yr);
#pragma unroll
        for (int i = 0; i < 8; i++) {
            V[0][i] += xr[i];
            V[1][i] += yr[i];
            V[2][i] = fmaf(xr[i], xr[i], V[2][i]);
            V[3][i] = fmaf(yr[i], yr[i], V[3][i]);
            V[4][i] = fmaf(xr[i], yr[i], V[4][i]);
        }
    }
    // first bottom row of the window
    load_row(r0 + 6, xr, yr);

    float sacc = 0.0f;

    for (int j = 0; j < RSTRIP; j++) {
        // add bottom row (r0 + j + 6), already in xr/yr
#pragma unroll
        for (int i = 0; i < 8; i++) {
            V[0][i] += xr[i];
            V[1][i] += yr[i];
            V[2][i] = fmaf(xr[i], xr[i], V[2][i]);
            V[3][i] = fmaf(yr[i], yr[i], V[3][i]);
            V[4][i] = fmaf(xr[i], yr[i], V[4][i]);
        }

        // prefetch: top row (subtract at iter end) and next bottom row
        // (consumed next iter) — xr/yr were just consumed, safe to overwrite.
        load_row(r0 + j, xo, yo);
        int rn = r0 + j + 7; if (rn > HH - 1) rn = HH - 1;  // clamped; dead on last iter
        load_row(rn, xr, yr);

        // halo: V cols 8..13 = lane+1's cols 0..5 (lane 63's valid outputs
        // never touch halo; its garbage feeds only masked pixels)
        float Vh[5][6];
#pragma unroll
        for (int q = 0; q < 5; q++)
#pragma unroll
            for (int i = 0; i < 6; i++) Vh[q][i] = __shfl_down(V[q][i], 1);

        // horizontal window init (cols 0..6), then slide across 8 outputs
        float H[5];
#pragma unroll
        for (int q = 0; q < 5; q++)
            H[q] = ((V[q][0] + V[q][1]) + (V[q][2] + V[q][3])) +
                   ((V[q][4] + V[q][5]) + V[q][6]);

#pragma unroll
        for (int i = 0; i < 8; i++) {
            float U0 = H[0], U1 = H[1], U2 = H[2], U3 = H[3], U4 = H[4];
            float A    = U0 * U1;
            float q01  = fmaf(U0, U0, U1 * U1);
            float num1 = fmaf(2.0f, A, D1);
            float den1 = q01 + D1;
            float num2 = fmaf(K49COV2, U4, fmaf(-COV2, A, D2));
            float s23  = U2 + U3;
            float den2 = fmaf(K49COV, s23, fmaf(-COVN, q01, D2));
            float S = (num1 * num2) * __builtin_amdgcn_rcpf(den1 * den2);
            sacc += (c0 + i < OW) ? S : 0.0f;
            if (i < 7) {
                // slide window i..i+6 -> i+1..i+7: add col i+7, drop col i
#pragma unroll
                for (int q = 0; q < 5; q++) {
                    float addv = (i == 0) ? V[q][7] : Vh[q][i - 1];
                    H[q] += addv - V[q][i];
                }
            }
        }

        // subtract top row (r0 + j)
#pragma unroll
        for (int i = 0; i < 8; i++) {
            V[0][i] -= xo[i];
            V[1][i] -= yo[i];
            V[2][i] = fmaf(-xo[i], xo[i], V[2][i]);
            V[3][i] = fmaf(-yo[i], yo[i], V[3][i]);
            V[4][i] = fmaf(-xo[i], yo[i], V[4][i]);
        }
    }

    // single-wave block: shuffle reduction, one double atomic per block
#pragma unroll
    for (int off = 32; off > 0; off >>= 1)
        sacc += __shfl_down(sacc, off);
    if (lane == 0) atomicAdd(acc, (double)sacc);
}

__global__ void ssim_finalize(const double* __restrict__ acc, float* __restrict__ out)
{
    out[0] = (float)(acc[0] / NPIX);
}

extern "C" void kernel_launch(void* const* d_in, const int* in_sizes, int n_in,
                              void* d_out, int out_size, void* d_ws, size_t ws_size,
                              hipStream_t stream)
{
    const float* X = (const float*)d_in[0];   // input_tensor (32,3,512,512) fp32
    const float* Y = (const float*)d_in[1];   // target       (32,3,512,512) fp32
    float* out = (float*)d_out;               // scalar fp32
    double* acc = (double*)d_ws;

    hipMemsetAsync(d_ws, 0, sizeof(double), stream);
    ssim_main<<<dim3(NSTRIP, NIMG), 64, 0, stream>>>(X, Y, acc);
    ssim_finalize<<<1, 1, 0, stream>>>(acc, out);
}

// Round 5
// 251.818 us; speedup vs baseline: 1.0051x; 1.0051x over previous
//
#include <hip/hip_runtime.h>

// SSIM (win=7, valid) fused single-pass kernel for (32,3,512,512) fp32 inputs.
// 96 images of 512x512 -> mean over 96x506x506 S map.
//
// R5: DRAM burst shaping. All prior rounds plateaued at ~2 TB/s HBM with
// nothing on-chip saturated -> diagnosis: ~8000 concurrent 0.5-2KB row
// streams look random at DRAM-page granularity. Fix: process 2 output rows
// per iteration so each of the wave's 4 streams advances in 4KB contiguous
// bursts (2 adjacent image rows, 8x dwordx4 back-to-back). Fully unrolled
// loop lets the compiler cluster bursts and rename double-buffers.
// Single-wave blocks, no LDS, no barriers in the loop (R4 structure).

namespace {
constexpr int W      = 512;
constexpr int HH     = 512;
constexpr int NIMG   = 96;
constexpr int OW     = 506;
constexpr int RSTRIP = 22;   // 23 * 22 = 506 output rows exactly
constexpr int NSTRIP = 23;
// S = (2 ux uy + C1)(2 vxy + C2) / ((ux^2+uy^2+C1)(vx+vy+C2)); with U = 49*u
// window sums, every term carries 1/2401 which cancels in the ratio:
constexpr float D1      = 0.2401f;                  // C1 * 49^2
constexpr float D2      = 2.1609f;                  // C2 * 49^2
constexpr float COVN    = 49.0f / 48.0f;            // NP/(NP-1)
constexpr float COV2    = 2.0f * COVN;
constexpr float K49COV  = 49.0f * COVN;
constexpr float K49COV2 = 2.0f * 49.0f * COVN;
constexpr double NPIX   = 96.0 * 506.0 * 506.0;     // 24,579,456
}

__global__ __launch_bounds__(64, 2) void ssim_main(const float* __restrict__ X,
                                                   const float* __restrict__ Y,
                                                   double* __restrict__ acc)
{
    const int lane = threadIdx.x;              // 0..63 (one wave per block)
    const int img  = blockIdx.y;
    const int r0   = blockIdx.x * RSTRIP;      // first output row of strip
    const int c0   = lane * 8;                 // this lane's first column

    const float* xb = X + (size_t)img * (W * HH) + c0;
    const float* yb = Y + (size_t)img * (W * HH) + c0;

    // vertical running sums over the 7-row window, per own column 0..7:
    // V[0]=sum x, V[1]=sum y, V[2]=sum x^2, V[3]=sum y^2, V[4]=sum x*y
    float V[5][8];
#pragma unroll
    for (int q = 0; q < 5; q++)
#pragma unroll
        for (int i = 0; i < 8; i++) V[q][i] = 0.0f;

    // load two ADJACENT image rows (one 4KB contiguous burst per array):
    // x row r, x row r+1, y row r, y row r+1 — 8 dwordx4 issued together.
    auto load2 = [&](int r, float (&dx)[2][8], float (&dy)[2][8]) {
        int ra = r;     if (ra > HH - 1) ra = HH - 1;
        int rb = r + 1; if (rb > HH - 1) rb = HH - 1;
        const float* pxa = xb + (size_t)ra * W;
        const float* pxb = xb + (size_t)rb * W;
        const float* pya = yb + (size_t)ra * W;
        const float* pyb = yb + (size_t)rb * W;
        float4 a0 = *(const float4*)pxa, a1 = *(const float4*)(pxa + 4);
        float4 b0 = *(const float4*)pxb, b1 = *(const float4*)(pxb + 4);
        float4 e0 = *(const float4*)pya, e1 = *(const float4*)(pya + 4);
        float4 f0 = *(const float4*)pyb, f1 = *(const float4*)(pyb + 4);
        dx[0][0]=a0.x; dx[0][1]=a0.y; dx[0][2]=a0.z; dx[0][3]=a0.w;
        dx[0][4]=a1.x; dx[0][5]=a1.y; dx[0][6]=a1.z; dx[0][7]=a1.w;
        dx[1][0]=b0.x; dx[1][1]=b0.y; dx[1][2]=b0.z; dx[1][3]=b0.w;
        dx[1][4]=b1.x; dx[1][5]=b1.y; dx[1][6]=b1.z; dx[1][7]=b1.w;
        dy[0][0]=e0.x; dy[0][1]=e0.y; dy[0][2]=e0.z; dy[0][3]=e0.w;
        dy[0][4]=e1.x; dy[0][5]=e1.y; dy[0][6]=e1.z; dy[0][7]=e1.w;
        dy[1][0]=f0.x; dy[1][1]=f0.y; dy[1][2]=f0.z; dy[1][3]=f0.w;
        dy[1][4]=f1.x; dy[1][5]=f1.y; dy[1][6]=f1.z; dy[1][7]=f1.w;
    };

    auto vadd = [&](const float (&xs)[8], const float (&ys)[8]) {
#pragma unroll
        for (int i = 0; i < 8; i++) {
            V[0][i] += xs[i];
            V[1][i] += ys[i];
            V[2][i] = fmaf(xs[i], xs[i], V[2][i]);
            V[3][i] = fmaf(ys[i], ys[i], V[3][i]);
            V[4][i] = fmaf(xs[i], ys[i], V[4][i]);
        }
    };
    auto vsub = [&](const float (&xs)[8], const float (&ys)[8]) {
#pragma unroll
        for (int i = 0; i < 8; i++) {
            V[0][i] -= xs[i];
            V[1][i] -= ys[i];
            V[2][i] = fmaf(-xs[i], xs[i], V[2][i]);
            V[3][i] = fmaf(-ys[i], ys[i], V[3][i]);
            V[4][i] = fmaf(-xs[i], ys[i], V[4][i]);
        }
    };

    float sacc = 0.0f;

    // horizontal 7-sum + SSIM over this lane's 8 output cols from current V
    auto ssim_row = [&]() {
        float Vh[5][6];
#pragma unroll
        for (int q = 0; q < 5; q++)
#pragma unroll
            for (int i = 0; i < 6; i++) Vh[q][i] = __shfl_down(V[q][i], 1);
        float H[5];
#pragma unroll
        for (int q = 0; q < 5; q++)
            H[q] = ((V[q][0] + V[q][1]) + (V[q][2] + V[q][3])) +
                   ((V[q][4] + V[q][5]) + V[q][6]);
#pragma unroll
        for (int i = 0; i < 8; i++) {
            float U0 = H[0], U1 = H[1], U2 = H[2], U3 = H[3], U4 = H[4];
            float A    = U0 * U1;
            float q01  = fmaf(U0, U0, U1 * U1);
            float num1 = fmaf(2.0f, A, D1);
            float den1 = q01 + D1;
            float num2 = fmaf(K49COV2, U4, fmaf(-COV2, A, D2));
            float s23  = U2 + U3;
            float den2 = fmaf(K49COV, s23, fmaf(-COVN, q01, D2));
            float S = (num1 * num2) * __builtin_amdgcn_rcpf(den1 * den2);
            sacc += (c0 + i < OW) ? S : 0.0f;
            if (i < 7) {
#pragma unroll
                for (int q = 0; q < 5; q++) {
                    float addv = (i == 0) ? V[q][7] : Vh[q][i - 1];
                    H[q] += addv - V[q][i];
                }
            }
        }
    };

    // warm-up: rows r0 .. r0+5 (three 2-row bursts)
    {
        float tx[2][8], ty[2][8];
#pragma unroll
        for (int k = 0; k < 3; k++) {
            load2(r0 + 2 * k, tx, ty);
            vadd(tx[0], ty[0]);
            vadd(tx[1], ty[1]);
        }
    }

    // current bottom pair: rows r0+6, r0+7
    float xc[2][8], yc[2][8];
    load2(r0 + 6, xc, yc);

#pragma unroll
    for (int jj = 0; jj < RSTRIP / 2; jj++) {
        const int j0 = r0 + 2 * jj;

        // bursts for this iter (top pair) and next iter (bottom pair),
        // issued up front; consumed after plenty of independent VALU work.
        float xo[2][8], yo[2][8], xn[2][8], yn[2][8];
        load2(j0, xo, yo);          // top rows j0, j0+1 (subtract later)
        load2(j0 + 8, xn, yn);      // next bottom rows j0+8, j0+9 (clamped)

        // output row j0: window rows j0..j0+6
        vadd(xc[0], yc[0]);
        ssim_row();
        // output row j0+1: window rows j0+1..j0+7
        vadd(xc[1], yc[1]);
        vsub(xo[0], yo[0]);
        ssim_row();
        // leave V = rows j0+2..j0+7 (6 rows) for next iteration
        vsub(xo[1], yo[1]);

        // rotate double-buffer (renamed by full unroll, no movs expected)
#pragma unroll
        for (int i = 0; i < 8; i++) {
            xc[0][i] = xn[0][i]; xc[1][i] = xn[1][i];
            yc[0][i] = yn[0][i]; yc[1][i] = yn[1][i];
        }
    }

    // single-wave block: shuffle reduction, one double atomic per block
#pragma unroll
    for (int off = 32; off > 0; off >>= 1)
        sacc += __shfl_down(sacc, off);
    if (lane == 0) atomicAdd(acc, (double)sacc);
}

__global__ void ssim_finalize(const double* __restrict__ acc, float* __restrict__ out)
{
    out[0] = (float)(acc[0] / NPIX);
}

extern "C" void kernel_launch(void* const* d_in, const int* in_sizes, int n_in,
                              void* d_out, int out_size, void* d_ws, size_t ws_size,
                              hipStream_t stream)
{
    const float* X = (const float*)d_in[0];   // input_tensor (32,3,512,512) fp32
    const float* Y = (const float*)d_in[1];   // target       (32,3,512,512) fp32
    float* out = (float*)d_out;               // scalar fp32
    double* acc = (double*)d_ws;

    hipMemsetAsync(d_ws, 0, sizeof(double), stream);
    ssim_main<<<dim3(NSTRIP, NIMG), 64, 0, stream>>>(X, Y, acc);
    ssim_finalize<<<1, 1, 0, stream>>>(acc, out);
}